// Round 6
// baseline (74946.692 us; speedup 1.0000x reference)
//
#include <hip/hip_runtime.h>
#include <math.h>

#define A_ 64
#define B_ 256
#define D_ 128
#define H_ 512
#define STEPS_ENC 64
#define STEPS_TOT (64 + 16384)   // 64 encoder steps + 256*64 decoder steps
#define NWG 32
#define NTHREADS 512             // 8 waves, 2 hidden units each
#define DYN_LDS 86016            // >80KB => exactly 1 WG/CU (LDS=160KB/CU)

// s_getreg immediate: id | offset<<6 | (width-1)<<11 ; HW_REG_XCC_ID = 20
#define XCC_GETREG_IMM (20 | (31 << 11))

typedef float f4v __attribute__((ext_vector_type(4)));

// workspace layout (float offsets) — kept identical to prior session for safety
#define OFF_XT    0
#define N_XT      (A_*D_*B_)
#define OFF_HT0   (OFF_XT + N_XT)
#define OFF_HT1   (OFF_HT0 + H_*B_)
#define OFF_CT    (OFF_HT1 + H_*B_)
#define OFF_HTAP  (OFF_CT + H_*B_)        // decoder h taps [256][512]
#define OFF_HB64  (OFF_HTAP + B_*H_)      // tagged h [2][512] u64
#define OFF_CINIT (OFF_HB64 + 4*H_)
#define OFF_ELECT (OFF_CINIT + H_)        // ints: [0..7] per-XCD counters, [8] winner

// tanh(x) = 1 - 2/(e^{2x}+1); exact at saturation
__device__ __forceinline__ float tanhfast(float x) {
  return 1.0f - 2.0f * __builtin_amdgcn_rcpf(__expf(2.0f * x) + 1.0f);
}

// PROVEN PROTOCOL (R0-R4, reverted after R5's sc0 hang): nt store writes
// through to the XCD-shared L2; nt loads never ALLOCATE into L1, and HB
// lines are only ever touched by nt ops, so polls read L2 fresh. buffer_inv
// every 64 spins stays as the liveness net. R5 lesson: scope-bit experiments
// (sc0) risk reading a DIFFERENT cache level than the store writes -> hang.
__device__ __forceinline__ unsigned long long load_nt(const unsigned long long* p) {
  unsigned long long v;
  asm volatile("global_load_dwordx2 %0, %1, off nt\n\ts_waitcnt vmcnt(0)"
               : "=&v"(v) : "v"(p) : "memory");
  return v;
}
__device__ __forceinline__ unsigned long long load_inv(const unsigned long long* p) {
  unsigned long long v;
  asm volatile("buffer_inv sc0\n\t"
               "global_load_dwordx2 %0, %1, off nt\n\ts_waitcnt vmcnt(0)"
               : "=&v"(v) : "v"(p) : "memory");
  return v;
}
__device__ __forceinline__ void store_nt(unsigned long long* p, unsigned long long v) {
  asm volatile("global_store_dwordx2 %0, %1, off nt" :: "v"(p), "v"(v) : "memory");
}

// DPP add helper: x += dpp_sel(x). VALU-speed (no LDS).
template<int CTRL>
__device__ __forceinline__ float dpp_add(float x) {
  int y = __builtin_amdgcn_update_dpp(0, __float_as_int(x), CTRL, 0xF, 0xF, false);
  return x + __int_as_float(y);
}
// 8-lane group all-sum (R3 correctness-proven): half_mirror, quad xor2, xor1.
__device__ __forceinline__ float grp8_allsum(float x) {
  x = dpp_add<0x141>(x);   // row_half_mirror
  x = dpp_add<0x4E>(x);    // quad_perm [2,3,0,1]  (xor 2)
  x = dpp_add<0xB1>(x);    // quad_perm [1,0,3,2]  (xor 1)
  return x;
}

// padded hstage: 64-float chunk v at 68v (R3-proven: stage writes contiguous;
// dot reads are 8 distinct 16B addrs, banks 4j mod 32 -> conflict-free).
#define HSP 68
#define HS_N (8 * HSP)   // 544 floats per parity buffer

// ---------------------------------------------------------------------------
// init0: seed tagged h (tag 0 = zero-state in parity 1, invalid in parity 0),
// reset election. Encoder h0/c0 are zeros so tag 0 carries h=0.0f.
// ---------------------------------------------------------------------------
__global__ void init0(float* __restrict__ ws) {
  unsigned long long* HB = (unsigned long long*)(ws + OFF_HB64);
  int* EL = (int*)(ws + OFF_ELECT);
  int j = threadIdx.x;                 // 512 threads
  HB[H_ + j] = 0ull;                   // parity 1: tag 0, h = 0.0f
  HB[j]      = 0xFFFFFFFF00000000ull;  // parity 0: invalid
  if (j < 8) EL[j] = 0;
  if (j == 8) EL[8] = -1;              // winner xcd
}

// ---------------------------------------------------------------------------
// One LSTM recurrence phase. R6 layout: 8 waves, wave v owns units
// u = 16w + 2v + n (n = l>>5). Lane (n = l>>5, g = (l>>3)&3, j = l&7) holds
// gate row R = g*512+u over h[64j,64j+64) and x[16j,16j+16) — R3's
// correctness-proven mapping, now with:
//  - __launch_bounds__(512,2): weights STAY in registers (R3's VGPR=64 cap
//    forced per-step weight reloads — its real regression).
//  - f4v ext-vector dot -> v_pk_fma_f32 (halves FMA issue count).
//  - 86KB LDS/WG forces 1 WG/CU: post-barrier compute phase is 2 waves/SIMD
//    instead of 4 -> halves the issue-bound phase (active-CU VALUBusy ~46%
//    in R2 showed issue pressure, not latency, dominates).
// Protocol (poll/store/barrier/parity) byte-identical to R2's proven loop.
// ---------------------------------------------------------------------------
template<int PHASE>
__device__ __forceinline__ void lstm_phase(
    const float* __restrict__ in0,
    const float* __restrict__ Wih, const float* __restrict__ Whh,
    const float* __restrict__ bih, const float* __restrict__ bhh,
    unsigned long long* __restrict__ HB, float* __restrict__ HTAP,
    float* hstage,                    // [2][HS_N] carved from dynamic LDS
    int w, int v, int l, float& c0, float& c1,
    float actA, float actB, float actC)
{
  const int j = l & 7;               // k-slice
  const int n = l >> 5;              // unit select within the wave's pair
  const int g = (l >> 3) & 3;        // gate 0=i 1=f 2=g~ 3=o
  const int u = (w << 4) + (v << 1) + n;
  const int R = (g << 9) + u;        // global gate row

  f4v wh[16];
#pragma unroll
  for (int k = 0; k < 16; ++k)
    wh[k] = *(const f4v*)&Whh[R * H_ + (j << 6) + (k << 2)];
  f4v wx[4];
#pragma unroll
  for (int k = 0; k < 4; ++k)
    wx[k] = *(const f4v*)&Wih[R * D_ + (j << 4) + (k << 2)];
  const float bias = (j == 0) ? (bih[R] + bhh[R]) : 0.f;  // counted once/row

  const int s0 = (PHASE == 0) ? 0 : STEPS_ENC;
  const int s1 = (PHASE == 0) ? STEPS_ENC : STEPS_TOT;

  for (int s = s0; s < s1; ++s) {
    // x loads — independent of h, issued before the poll to overlap
    const float* xp;
    if (PHASE == 0) {
      xp = in0 + (s * B_ + 255) * D_;                     // x_t = input[t,255,:]
    } else {
      const int sd = s - STEPS_ENC;
      xp = in0 + ((sd & 63) * B_ + (255 - (sd >> 6))) * D_;
    }
    f4v xv0 = *(const f4v*)(xp + (j << 4));
    f4v xv1 = *(const f4v*)(xp + (j << 4) + 4);
    f4v xv2 = *(const f4v*)(xp + (j << 4) + 8);
    f4v xv3 = *(const f4v*)(xp + (j << 4) + 12);

    // poll h_{s-1}: 64 slots, one lane each (nt; inv net 1/64 spins)
    unsigned long long* slot = &HB[(((s + 1) & 1) << 9) + (v << 6) + l];
    unsigned long long pk;
    int spins = 0;
    for (;;) {
      pk = ((++spins & 63) == 0) ? load_inv(slot) : load_nt(slot);
      if (__all((unsigned)(pk >> 32) == (unsigned)s)) break;
    }
    float* hbuf = hstage + (s & 1) * HS_N;
    hbuf[v * HSP + l] = __uint_as_float((unsigned)pk);

    // x-partial (pk_fma) while the stage settles
    f4v acc4 = wx[0] * xv0;
    acc4 += wx[1] * xv1;
    acc4 += wx[2] * xv2;
    acc4 += wx[3] * xv3;

    __syncthreads();                      // the ONE barrier per step

    // full-H dot: lane j reads h[64j..64j+64); pk_fma pairs
    const f4v* hp = (const f4v*)&hbuf[j * HSP];
#pragma unroll
    for (int k = 0; k < 16; ++k)
      acc4 += wh[k] * hp[k];
    float acc = bias + ((acc4.x + acc4.y) + (acc4.z + acc4.w));

    // 8-lane all-sum within each (unit,gate) group
    float a = grp8_allsum(acc);
    // unified activation: i,f,o -> sigmoid; g~ -> tanh (per-lane constants)
    a = fmaf(actA, __builtin_amdgcn_rcpf(__expf(actB * a) + 1.0f), actC);
    // gather the 8 group sums (gate g of unit n sits at lane 32n + 8g)
    float ai0 = __shfl(a, 0),  af0 = __shfl(a, 8);
    float ag0 = __shfl(a, 16), ao0 = __shfl(a, 24);
    float ai1 = __shfl(a, 32), af1 = __shfl(a, 40);
    float ag1 = __shfl(a, 48), ao1 = __shfl(a, 56);
    c0 = af0 * c0 + ai0 * ag0;
    c1 = af1 * c1 + ai1 * ag1;
    float hn0 = ao0 * tanhfast(c0);
    float hn1 = ao1 * tanhfast(c1);
    if ((l & 31) == 0) {                  // lanes 0 and 32: one unit each
      float hnm = n ? hn1 : hn0;
      // h taps every 64 steps: s=63 -> q=0 (encoder final), s=127 -> q=1, ...
      if ((s & 63) == 63) {
        int q = s >> 6;
        if (q < 256) HTAP[q * H_ + u] = hnm;
      }
      unsigned long long opk =
          ((unsigned long long)(unsigned)(s + 1) << 32) | __float_as_uint(hnm);
      store_nt(&HB[((s & 1) << 9) + u], opk);
    }
  }
}

// ---------------------------------------------------------------------------
// fused persistent kernel: 256 WGs x 512 threads, 86KB LDS => exactly one WG
// per CU (deterministic placement; the winning XCD's 32 WGs sit on 32
// distinct CUs). The 32 on the elected XCD run 64 encoder + 16384 decoder
// sequential steps; others exit.
// ---------------------------------------------------------------------------
__global__ __launch_bounds__(NTHREADS, 2) void fused(
    const float* __restrict__ in0,
    const float* __restrict__ eWih, const float* __restrict__ eWhh,
    const float* __restrict__ ebih, const float* __restrict__ ebhh,
    const float* __restrict__ dWih, const float* __restrict__ dWhh,
    const float* __restrict__ dbih, const float* __restrict__ dbhh,
    float* __restrict__ ws)
{
  unsigned long long* HB = (unsigned long long*)(ws + OFF_HB64);
  float* HTAP = ws + OFF_HTAP;

  extern __shared__ float smem[];     // 86KB: hstage (4.4KB) + occupancy pad
  float* hstage = smem;               // [2][HS_N]
  __shared__ int role;

  const int tid = threadIdx.x;

  // ---- election: first XCD to seat 32 WGs wins; its ranks 0..31 decode ----
  if (tid == 0) {
    unsigned xcc = ((unsigned)__builtin_amdgcn_s_getreg(XCC_GETREG_IMM)) & 7u;
    int* EL = (int*)(ws + OFF_ELECT);
    int r = __hip_atomic_fetch_add(&EL[xcc], 1, __ATOMIC_RELAXED,
                                   __HIP_MEMORY_SCOPE_AGENT);
    int myrole = -1;
    if (r < NWG) {
      if (r == NWG - 1) {
        int exp = -1;
        __hip_atomic_compare_exchange_strong(&EL[8], &exp, (int)xcc,
            __ATOMIC_RELAXED, __ATOMIC_RELAXED, __HIP_MEMORY_SCOPE_AGENT);
      }
      int wx;
      do {
        wx = __hip_atomic_load(&EL[8], __ATOMIC_RELAXED, __HIP_MEMORY_SCOPE_AGENT);
        if (wx == -1) __builtin_amdgcn_s_sleep(2);
      } while (wx == -1);
      if (wx == (int)xcc) myrole = r;
    }
    role = myrole;
  }
  __syncthreads();
  if (role < 0) return;               // uniform per WG
  const int w = role;

  const int v = tid >> 6;             // wave 0..7 -> units 16w+2v, 16w+2v+1
  const int l = tid & 63;             // lane

  // per-lane unified-activation constants by gate ((l>>3)&3): 2 = g~ (tanh)
  const int gate = (l >> 3) & 3;
  const float actA = (gate == 2) ? -2.0f :  1.0f;
  const float actB = (gate == 2) ?  2.0f : -1.0f;
  const float actC = (gate == 2) ?  1.0f :  0.0f;

  float c0 = 0.f, c1 = 0.f;           // encoder starts from h0 = c0 = 0

  lstm_phase<0>(in0, eWih, eWhh, ebih, ebhh, HB, HTAP, hstage,
                w, v, l, c0, c1, actA, actB, actC);
  lstm_phase<1>(in0, dWih, dWhh, dbih, dbhh, HB, HTAP, hstage,
                w, v, l, c0, c1, actA, actB, actC);
}

// ---------------------------------------------------------------------------
// out_proj: outs[255-b] = Htap[255-b] @ lin_W^T + lin_b, broadcast over a.
// ---------------------------------------------------------------------------
__global__ __launch_bounds__(128) void out_proj(
    const float* __restrict__ ws, const float* __restrict__ linW,
    const float* __restrict__ linb, float* __restrict__ out) {
  const float* HTAP = ws + OFF_HTAP;
  __shared__ float hs[H_];
  const int b = blockIdx.x;
  const int i = 255 - b;
  const int d = threadIdx.x;
  *(float4*)&hs[4 * d] = *(const float4*)&HTAP[i * H_ + 4 * d];
  __syncthreads();
  float acc = linb[d];
#pragma unroll 8
  for (int k = 0; k < H_; k += 4) {
    float4 w4 = *(const float4*)&linW[d * H_ + k];
    acc += w4.x * hs[k] + w4.y * hs[k + 1] + w4.z * hs[k + 2] + w4.w * hs[k + 3];
  }
  for (int a = 0; a < A_; ++a)
    out[(a * B_ + b) * D_ + d] = acc;
}

// ---------------------------------------------------------------------------
extern "C" void kernel_launch(void* const* d_in, const int* in_sizes, int n_in,
                              void* d_out, int out_size, void* d_ws, size_t ws_size,
                              hipStream_t stream) {
  const float* in0  = (const float*)d_in[0];
  const float* eWih = (const float*)d_in[1];
  const float* eWhh = (const float*)d_in[2];
  const float* ebih = (const float*)d_in[3];
  const float* ebhh = (const float*)d_in[4];
  const float* dWih = (const float*)d_in[5];
  const float* dWhh = (const float*)d_in[6];
  const float* dbih = (const float*)d_in[7];
  const float* dbhh = (const float*)d_in[8];
  const float* linW = (const float*)d_in[9];
  const float* linb = (const float*)d_in[10];
  float* ws = (float*)d_ws;
  float* out = (float*)d_out;

  // allow >64KB dynamic LDS (immediate API call; not a stream op, so safe
  // under graph capture)
  hipFuncSetAttribute((const void*)fused,
                      hipFuncAttributeMaxDynamicSharedMemorySize, DYN_LDS);

  init0<<<1, 512, 0, stream>>>(ws);
  fused<<<256, NTHREADS, DYN_LDS, stream>>>(in0, eWih, eWhh, ebih, ebhh,
                                            dWih, dWhh, dbih, dbhh, ws);
  out_proj<<<256, 128, 0, stream>>>(ws, linW, linb, out);
}

// Round 7
// 18296.858 us; speedup vs baseline: 4.0962x; 4.0962x over previous
//
#include <hip/hip_runtime.h>
#include <math.h>

#define A_ 64
#define B_ 256
#define D_ 128
#define H_ 512
#define STEPS_ENC 64
#define STEPS_TOT (64 + 16384)   // 64 encoder steps + 256*64 decoder steps
#define NWG 32
#define NTHREADS 1024            // 16 waves, 1 hidden unit each (R2-proven)

// s_getreg immediate: id | offset<<6 | (width-1)<<11 ; HW_REG_XCC_ID = 20
#define XCC_GETREG_IMM (20 | (31 << 11))

// workspace layout (float offsets) — kept identical to prior session for safety
#define OFF_XT    0
#define N_XT      (A_*D_*B_)
#define OFF_HT0   (OFF_XT + N_XT)
#define OFF_HT1   (OFF_HT0 + H_*B_)
#define OFF_CT    (OFF_HT1 + H_*B_)
#define OFF_HTAP  (OFF_CT + H_*B_)        // decoder h taps [256][512]
#define OFF_HB64  (OFF_HTAP + B_*H_)      // tagged h [2][512] u64
#define OFF_CINIT (OFF_HB64 + 4*H_)
#define OFF_ELECT (OFF_CINIT + H_)        // ints: [0..7] per-XCD counters, [8] winner

// tanh(x) = 1 - 2/(e^{2x}+1); exact at saturation
__device__ __forceinline__ float tanhfast(float x) {
  return 1.0f - 2.0f * __builtin_amdgcn_rcpf(__expf(2.0f * x) + 1.0f);
}

// R7 PROTOCOL ASM — same instructions as the R0-R4-proven nt+inv protocol,
// but WITHOUT "memory" clobbers. Rationale (R2 counter evidence): with the
// clobber, the per-lane weight set (40 floats) could never be treated as
// loop-invariant — VGPR_Count=40 proves weights were re-fetched from global
// INSIDE the step loop, and each poll's vmcnt(0) drained those reloads:
// the hidden ~1000cy/step term invariant across R0-R4.
// Safety without the clobber: volatile asms remain ordered among themselves
// (producer store_nt precedes the next poll's load_nt), pk data-dependence
// orders the LDS stage, and __syncthreads orders LDS visibility. The polled
// HB lines are touched ONLY by these asm ops. Weights/x/biases are
// read-only, so letting the compiler keep them in registers is sound.
__device__ __forceinline__ unsigned long long load_nt(const unsigned long long* p) {
  unsigned long long v;
  asm volatile("global_load_dwordx2 %0, %1, off nt\n\ts_waitcnt vmcnt(0)"
               : "=&v"(v) : "v"(p));
  return v;
}
// liveness net: L1 invalidate + load. 1/64 spins (round-5-proven semantics).
__device__ __forceinline__ unsigned long long load_inv(const unsigned long long* p) {
  unsigned long long v;
  asm volatile("buffer_inv sc0\n\t"
               "global_load_dwordx2 %0, %1, off nt\n\ts_waitcnt vmcnt(0)"
               : "=&v"(v) : "v"(p));
  return v;
}
__device__ __forceinline__ void store_nt(unsigned long long* p, unsigned long long v) {
  asm volatile("global_store_dwordx2 %0, %1, off nt" :: "v"(p), "v"(v));
}

// DPP rotate-reduce within each 16-lane row: after ror{8,4,2,1} add chain,
// EVERY lane of the row holds the 16-lane sum. VALU-speed (no LDS).
template<int CTRL>
__device__ __forceinline__ float dpp_ror_add(float x) {
  int y = __builtin_amdgcn_update_dpp(0, __float_as_int(x), CTRL, 0xF, 0xF, false);
  return x + __int_as_float(y);
}
__device__ __forceinline__ float row_allsum16(float x) {
  x = dpp_ror_add<0x128>(x);   // row_ror:8
  x = dpp_ror_add<0x124>(x);   // row_ror:4
  x = dpp_ror_add<0x122>(x);   // row_ror:2
  x = dpp_ror_add<0x121>(x);   // row_ror:1
  return x;
}

// padded hstage: chunk c = k>>5 stored at 36c + (k&31) (R2-proven layout).
#define HSP 36
#define HS_N (16 * HSP)   // 576 floats per parity buffer

// ---------------------------------------------------------------------------
// init0: seed tagged h (tag 0 = zero-state in parity 1, invalid in parity 0),
// reset election. Encoder h0/c0 are zeros so tag 0 carries h=0.0f.
// ---------------------------------------------------------------------------
__global__ void init0(float* __restrict__ ws) {
  unsigned long long* HB = (unsigned long long*)(ws + OFF_HB64);
  int* EL = (int*)(ws + OFF_ELECT);
  int j = threadIdx.x;                 // 512 threads
  HB[H_ + j] = 0ull;                   // parity 1: tag 0, h = 0.0f
  HB[j]      = 0xFFFFFFFF00000000ull;  // parity 0: invalid
  if (j < 8) EL[j] = 0;
  if (j == 8) EL[8] = -1;              // winner xcd
}

// ---------------------------------------------------------------------------
// One LSTM recurrence phase — R2-proven skeleton. Wave v owns hidden unit
// u = 16w+v; lane (g = l>>4, j = l&15) holds gate row R = g*512+u over
// h[32j,32j+32) and x[8j,8j+8). Only R7 deltas vs R2: clobber-free asm,
// launch_bounds(1024,1) on the kernel (register residency), dual-acc dot
// (R4-verified).
// ---------------------------------------------------------------------------
template<int PHASE>
__device__ __forceinline__ void lstm_phase(
    const float* __restrict__ in0,
    const float* __restrict__ Wih, const float* __restrict__ Whh,
    const float* __restrict__ bih, const float* __restrict__ bhh,
    unsigned long long* __restrict__ HB, float* __restrict__ HTAP,
    float* hstage,                    // [2][HS_N]
    int w, int v, int l, float& c,
    float actA, float actB, float actC)
{
  const int g = l >> 4;              // gate: 0=i 1=f 2=g~ 3=o
  const int j = l & 15;              // reduction lane / k-slice
  const int u = (w << 4) + v;        // hidden unit owned by this wave
  const int R = (g << 9) + u;        // global gate row

  float4 wh[8];
#pragma unroll
  for (int k = 0; k < 8; ++k)
    wh[k] = *(const float4*)&Whh[R * H_ + (j << 5) + (k << 2)];
  float4 wx0 = *(const float4*)&Wih[R * D_ + (j << 3)];
  float4 wx1 = *(const float4*)&Wih[R * D_ + (j << 3) + 4];
  const float bias = (j == 0) ? (bih[R] + bhh[R]) : 0.f;  // counted once/row

  const int pe = (v << 5) + (l & 31);   // polled element (2 lanes per element)

  const int s0 = (PHASE == 0) ? 0 : STEPS_ENC;
  const int s1 = (PHASE == 0) ? STEPS_ENC : STEPS_TOT;

  for (int s = s0; s < s1; ++s) {
    // x loads — independent of h, issued before the poll to overlap
    const float* xp;
    if (PHASE == 0) {
      xp = in0 + (s * B_ + 255) * D_;                     // x_t = input[t,255,:]
    } else {
      const int sd = s - STEPS_ENC;
      xp = in0 + ((sd & 63) * B_ + (255 - (sd >> 6))) * D_;
    }
    float4 x0 = *(const float4*)(xp + (j << 3));
    float4 x1 = *(const float4*)(xp + (j << 3) + 4);

    // poll h_{s-1}: nt loads from the shared L2; inv fallback 1/64 spins
    unsigned long long* slot = &HB[(((s + 1) & 1) << 9) + pe];
    unsigned long long pk;
    int spins = 0;
    for (;;) {
      pk = ((++spins & 63) == 0) ? load_inv(slot) : load_nt(slot);
      if (__all((unsigned)(pk >> 32) == (unsigned)s)) break;
    }
    float* hbuf = hstage + (s & 1) * HS_N;
    if (l < 32) hbuf[(v * HSP) + (l & 31)] = __uint_as_float((unsigned)pk);

    // bias + x contribution while the stage settles
    float acc0 = bias
               + wx0.x * x0.x + wx0.y * x0.y + wx0.z * x0.z + wx0.w * x0.w
               + wx1.x * x1.x + wx1.y * x1.y + wx1.z * x1.z + wx1.w * x1.w;

    __syncthreads();                      // the ONE barrier per step

    // full-H dot, dual accumulators to halve the FMA dep chain
    const float4* hp = (const float4*)&hbuf[j * HSP];
    float acc1 = 0.f;
#pragma unroll
    for (int k = 0; k < 8; k += 2) {
      float4 h4a = hp[k];
      float4 h4b = hp[k + 1];
      acc0 += wh[k].x * h4a.x + wh[k].y * h4a.y
            + wh[k].z * h4a.z + wh[k].w * h4a.w;
      acc1 += wh[k + 1].x * h4b.x + wh[k + 1].y * h4b.y
            + wh[k + 1].z * h4b.z + wh[k + 1].w * h4b.w;
    }

    // 16-lane rotate-reduce: every lane of group g now holds gate-g sum
    float a = row_allsum16(acc0 + acc1);
    // unified activation: i,f,o -> sigmoid; g~ -> tanh (per-lane constants)
    a = fmaf(actA, __builtin_amdgcn_rcpf(__expf(actB * a) + 1.0f), actC);
    // gather the 4 gates (group-uniform values -> broadcast)
    float ai = __shfl(a, 0);
    float af = __shfl(a, 16);
    float ag = __shfl(a, 32);
    float ao = __shfl(a, 48);
    c = af * c + ai * ag;                 // uniform across the wave
    float hn = ao * tanhfast(c);
    if (l == 0) {
      // h taps every 64 steps: s=63 -> q=0 (encoder final), s=127 -> q=1, ...
      if ((s & 63) == 63) {
        int q = s >> 6;
        if (q < 256) HTAP[q * H_ + u] = hn;
      }
      unsigned long long opk =
          ((unsigned long long)(unsigned)(s + 1) << 32) | __float_as_uint(hn);
      store_nt(&HB[((s & 1) << 9) + u], opk);
    }
  }
}

// ---------------------------------------------------------------------------
// fused persistent kernel: 256 WGs launched; the 32 on one elected XCD run
// 64 encoder + 16384 decoder sequential steps; others exit.
// __launch_bounds__(1024, 1): occupancy floor of 1 wave/EU relaxes the
// register allocator so the ~90 live values (40 weight floats + temps) stay
// in VGPRs instead of being re-fetched from global inside the step loop.
// VALIDITY GATE for this round: VGPR_Count must rise to >=96 (was 40).
// ---------------------------------------------------------------------------
__global__ __launch_bounds__(NTHREADS, 1) void fused(
    const float* __restrict__ in0,
    const float* __restrict__ eWih, const float* __restrict__ eWhh,
    const float* __restrict__ ebih, const float* __restrict__ ebhh,
    const float* __restrict__ dWih, const float* __restrict__ dWhh,
    const float* __restrict__ dbih, const float* __restrict__ dbhh,
    float* __restrict__ ws)
{
  unsigned long long* HB = (unsigned long long*)(ws + OFF_HB64);
  float* HTAP = ws + OFF_HTAP;

  __shared__ __align__(16) float hstage[2][HS_N];  // parity double-buffered
  __shared__ int role;

  const int tid = threadIdx.x;

  // ---- election: first XCD to seat 32 WGs wins; its ranks 0..31 decode ----
  if (tid == 0) {
    unsigned xcc = ((unsigned)__builtin_amdgcn_s_getreg(XCC_GETREG_IMM)) & 7u;
    int* EL = (int*)(ws + OFF_ELECT);
    int r = __hip_atomic_fetch_add(&EL[xcc], 1, __ATOMIC_RELAXED,
                                   __HIP_MEMORY_SCOPE_AGENT);
    int myrole = -1;
    if (r < NWG) {
      if (r == NWG - 1) {
        int exp = -1;
        __hip_atomic_compare_exchange_strong(&EL[8], &exp, (int)xcc,
            __ATOMIC_RELAXED, __ATOMIC_RELAXED, __HIP_MEMORY_SCOPE_AGENT);
      }
      int wx;
      do {
        wx = __hip_atomic_load(&EL[8], __ATOMIC_RELAXED, __HIP_MEMORY_SCOPE_AGENT);
        if (wx == -1) __builtin_amdgcn_s_sleep(2);
      } while (wx == -1);
      if (wx == (int)xcc) myrole = r;
    }
    role = myrole;
  }
  __syncthreads();
  if (role < 0) return;               // uniform per WG
  const int w = role;

  const int v = tid >> 6;             // wave -> hidden unit 16w+v
  const int l = tid & 63;             // lane

  // per-lane unified-activation constants by gate (l>>4): 0=i,1=f,2=g,3=o
  const int gate = l >> 4;
  const float actA = (gate == 2) ? -2.0f :  1.0f;
  const float actB = (gate == 2) ?  2.0f : -1.0f;
  const float actC = (gate == 2) ?  1.0f :  0.0f;

  float c = 0.f;                      // encoder starts from h0 = c0 = 0

  lstm_phase<0>(in0, eWih, eWhh, ebih, ebhh, HB, HTAP, &hstage[0][0],
                w, v, l, c, actA, actB, actC);
  lstm_phase<1>(in0, dWih, dWhh, dbih, dbhh, HB, HTAP, &hstage[0][0],
                w, v, l, c, actA, actB, actC);
}

// ---------------------------------------------------------------------------
// out_proj: outs[255-b] = Htap[255-b] @ lin_W^T + lin_b, broadcast over a.
// ---------------------------------------------------------------------------
__global__ __launch_bounds__(128) void out_proj(
    const float* __restrict__ ws, const float* __restrict__ linW,
    const float* __restrict__ linb, float* __restrict__ out) {
  const float* HTAP = ws + OFF_HTAP;
  __shared__ float hs[H_];
  const int b = blockIdx.x;
  const int i = 255 - b;
  const int d = threadIdx.x;
  *(float4*)&hs[4 * d] = *(const float4*)&HTAP[i * H_ + 4 * d];
  __syncthreads();
  float acc = linb[d];
#pragma unroll 8
  for (int k = 0; k < H_; k += 4) {
    float4 w4 = *(const float4*)&linW[d * H_ + k];
    acc += w4.x * hs[k] + w4.y * hs[k + 1] + w4.z * hs[k + 2] + w4.w * hs[k + 3];
  }
  for (int a = 0; a < A_; ++a)
    out[(a * B_ + b) * D_ + d] = acc;
}

// ---------------------------------------------------------------------------
extern "C" void kernel_launch(void* const* d_in, const int* in_sizes, int n_in,
                              void* d_out, int out_size, void* d_ws, size_t ws_size,
                              hipStream_t stream) {
  const float* in0  = (const float*)d_in[0];
  const float* eWih = (const float*)d_in[1];
  const float* eWhh = (const float*)d_in[2];
  const float* ebih = (const float*)d_in[3];
  const float* ebhh = (const float*)d_in[4];
  const float* dWih = (const float*)d_in[5];
  const float* dWhh = (const float*)d_in[6];
  const float* dbih = (const float*)d_in[7];
  const float* dbhh = (const float*)d_in[8];
  const float* linW = (const float*)d_in[9];
  const float* linb = (const float*)d_in[10];
  float* ws = (float*)d_ws;
  float* out = (float*)d_out;

  init0<<<1, 512, 0, stream>>>(ws);
  fused<<<256, NTHREADS, 0, stream>>>(in0, eWih, eWhh, ebih, ebhh,
                                      dWih, dWhh, dbih, dbhh, ws);
  out_proj<<<256, 128, 0, stream>>>(ws, linW, linb, out);
}